// Round 1
// baseline (73.664 us; speedup 1.0000x reference)
//
#include <hip/hip_runtime.h>

// Problem constants (from reference)
#define SOM_M 256
#define SOM_N 256
#define SOM_DIM 512
#define SOM_ROWS (SOM_M * SOM_N)          // 65536
#define SOM_ELEMS (SOM_ROWS * SOM_DIM)    // 33554432

// ---------------- Kernel 1: per-block BMU partial argmin ----------------
// One wave (64 lanes) per row; lane loads 8 floats (2x float4), butterfly
// reduce sum of squared diffs; block writes (min_dist, min_idx) partial.
__global__ __launch_bounds__(256) void som_bmu_partial(
    const float* __restrict__ w, const float* __restrict__ in,
    float* __restrict__ pd, int* __restrict__ pi) {
  __shared__ float s_in[SOM_DIM];
  for (int i = threadIdx.x; i < SOM_DIM; i += blockDim.x) s_in[i] = in[i];
  __syncthreads();

  const int wave = threadIdx.x >> 6;
  const int lane = threadIdx.x & 63;
  const int wavesPerBlock = blockDim.x >> 6;
  const int globalWave = blockIdx.x * wavesPerBlock + wave;
  const int nWaves = gridDim.x * wavesPerBlock;

  float best = 3.4e38f;
  int bestIdx = 0x7FFFFFFF;

  const float4* in4 = (const float4*)s_in;
  for (int row = globalWave; row < SOM_ROWS; row += nWaves) {
    const float4* wr = (const float4*)(w + (size_t)row * SOM_DIM);
    float acc = 0.f;
#pragma unroll
    for (int k = 0; k < 2; ++k) {
      float4 wv = wr[lane + 64 * k];
      float4 iv = in4[lane + 64 * k];
      float dx = wv.x - iv.x;
      float dy = wv.y - iv.y;
      float dz = wv.z - iv.z;
      float dw = wv.w - iv.w;
      acc += dx * dx + dy * dy + dz * dz + dw * dw;
    }
    // full butterfly: all 64 lanes end with the row's sum
#pragma unroll
    for (int off = 32; off; off >>= 1) acc += __shfl_xor(acc, off, 64);
    // rows visited in increasing order per wave -> strict < keeps first min
    if (acc < best) { best = acc; bestIdx = row; }
  }

  __shared__ float sb[8];
  __shared__ int si[8];
  if (lane == 0) { sb[wave] = best; si[wave] = bestIdx; }
  __syncthreads();
  if (threadIdx.x == 0) {
    float b = sb[0];
    int bi = si[0];
    for (int k = 1; k < wavesPerBlock; ++k) {
      if (sb[k] < b || (sb[k] == b && si[k] < bi)) { b = sb[k]; bi = si[k]; }
    }
    pd[blockIdx.x] = b;
    pi[blockIdx.x] = bi;
  }
}

// ---------------- Kernel 2: final reduce + bmu_loc ----------------
__global__ __launch_bounds__(256) void som_bmu_final(
    const float* __restrict__ pd, const int* __restrict__ pi, int nb,
    float* __restrict__ out, int* __restrict__ bmu) {
  float best = 3.4e38f;
  int bi = 0x7FFFFFFF;
  for (int i = threadIdx.x; i < nb; i += blockDim.x) {
    float d = pd[i];
    int idx = pi[i];
    if (d < best || (d == best && idx < bi)) { best = d; bi = idx; }
  }
  __shared__ float sd[256];
  __shared__ int sx[256];
  sd[threadIdx.x] = best;
  sx[threadIdx.x] = bi;
  __syncthreads();
  for (int s = 128; s; s >>= 1) {
    if ((int)threadIdx.x < s) {
      float od = sd[threadIdx.x + s];
      int ox = sx[threadIdx.x + s];
      if (od < sd[threadIdx.x] || (od == sd[threadIdx.x] && ox < sx[threadIdx.x])) {
        sd[threadIdx.x] = od;
        sx[threadIdx.x] = ox;
      }
    }
    __syncthreads();
  }
  if (threadIdx.x == 0) {
    int idx = sx[0];
    int r = idx >> 8;   // N = 256
    int c = idx & 255;
    out[0] = (float)r;  // bmu_loc as promoted float32 output
    out[1] = (float)c;
    bmu[0] = r;
    bmu[1] = c;
  }
}

// ---------------- Kernel 3: weight update ----------------
// new_w = w + alpha_op * exp(-bmu_dist_sq / sigma_op^2) * (in - w)
__global__ __launch_bounds__(256) void som_update(
    const float* __restrict__ w, const float* __restrict__ in,
    const int* __restrict__ epoch_p, const int* __restrict__ bmu,
    float* __restrict__ out_w /* = d_out + 2, 8B aligned */) {
  const float lr = 1.0f - (float)epoch_p[0] / 100.0f;
  const float alpha_op = 0.3f * lr;
  const float sigma_op = 128.0f * lr;
  const float inv_s2 = 1.0f / (sigma_op * sigma_op);
  const int br = bmu[0];
  const int bc = bmu[1];

  const float4* w4 = (const float4*)w;
  const float4* in4 = (const float4*)in;
  float2* o2 = (float2*)out_w;  // out+2 is only 8B-aligned -> float2 stores

  const int total4 = SOM_ELEMS / 4;  // 8388608
  const int stride = gridDim.x * blockDim.x;
  for (int i = blockIdx.x * blockDim.x + threadIdx.x; i < total4; i += stride) {
    const int elem = i << 2;
    const int row = elem >> 9;            // DIM = 512
    const int c4 = (elem & 511) >> 2;     // float4 index within row
    const int rr = (row >> 8) - br;
    const int cc = (row & 255) - bc;
    const float d2 = (float)(rr * rr + cc * cc);
    const float mult = alpha_op * __expf(-d2 * inv_s2);

    float4 wv = w4[i];
    float4 iv = in4[c4];
    float2 a, b;
    a.x = wv.x + mult * (iv.x - wv.x);
    a.y = wv.y + mult * (iv.y - wv.y);
    b.x = wv.z + mult * (iv.z - wv.z);
    b.y = wv.w + mult * (iv.w - wv.w);
    o2[2 * i] = a;
    o2[2 * i + 1] = b;
  }
}

extern "C" void kernel_launch(void* const* d_in, const int* in_sizes, int n_in,
                              void* d_out, int out_size, void* d_ws, size_t ws_size,
                              hipStream_t stream) {
  const float* input_vector = (const float*)d_in[0];
  const float* weights = (const float*)d_in[1];
  const int* epoch = (const int*)d_in[2];
  float* out = (float*)d_out;

  // workspace layout
  const int NB = 2048;
  float* pd = (float*)d_ws;                   // [NB]
  int* pi = (int*)((char*)d_ws + NB * 4);     // [NB]
  int* bmu = (int*)((char*)d_ws + 2 * NB * 4);// [2]

  som_bmu_partial<<<NB, 256, 0, stream>>>(weights, input_vector, pd, pi);
  som_bmu_final<<<1, 256, 0, stream>>>(pd, pi, NB, out, bmu);
  som_update<<<2048, 256, 0, stream>>>(weights, input_vector, epoch, bmu, out + 2);
}